// Round 5
// baseline (78.893 us; speedup 1.0000x reference)
//
#include <hip/hip_runtime.h>
#include <hip/hip_bf16.h>
#include <math.h>

// EGNN layer, collapsed. Reference multiplies the edge tensor by eye(N)
// before the sum over axis -2, so h_e[b,i,:] = he[b,i,i,:] -- only diagonal
// edges survive, and x[i]-x[i]=0 so norm = sqrt(EPS) exactly:
//   e_in = [h_i, h_i, sqrt(EPS)]              (65)
//   t1   = silu(e_in @ We1 + be1)             (32)
//   t2   = silu(t1  @ We2 + be2)              (32)
//   att  = sigmoid(dot(t2, Wa) + ba)          (1)
//   he   = att * t2                           (32)
//   u    = silu([h_i, he] @ Wn1 + bn1)        (32)
//   out  = u @ Wn2 + bn2                      (32)
// Inputs fp32, d_out fp32 (verified rounds 0-3). d_out = out[B*N*32] ++ x[B*N*3].
//
// Round-3 counters: dur_us 78.2 is dominated by harness 0xAA re-poison fills
// of the 256 MiB workspace (2 x 40 us @ 84% HBM peak); kernel itself is ~2 us
// and absent from top-5. This round (re-run; round 4 was an infra failure):
// shortened kernel critical path (4-way split fma chains) as a discriminator --
// if dur_us doesn't move, the bench window is at the harness re-poison floor.

#define SQRT_EPS 0.003162277660168379f  // sqrt(1e-5)

__device__ __forceinline__ float silu_f(float v) { return v / (1.0f + expf(-v)); }

__global__ __launch_bounds__(256) void egnn_diag_kernel(
    const float* __restrict__ h,    // [n_nodes, 32]
    const float* __restrict__ x,    // [n_nodes, 3]
    const float* __restrict__ We1,  // [65, 32]
    const float* __restrict__ be1,  // [32]
    const float* __restrict__ We2,  // [32, 32]
    const float* __restrict__ be2,  // [32]
    const float* __restrict__ Wa,   // [32, 1]
    const float* __restrict__ ba,   // [1]
    const float* __restrict__ Wn1,  // [64, 32]
    const float* __restrict__ bn1,  // [32]
    const float* __restrict__ Wn2,  // [32, 32]
    const float* __restrict__ bn2,  // [32]
    float* __restrict__ out,        // [n_nodes*32] then [n_nodes*3]
    int n_nodes)
{
    const int tid  = blockIdx.x * blockDim.x + threadIdx.x;
    const int node = tid >> 5;
    const int k    = tid & 31;  // output channel owned by this lane
    if (node >= n_nodes) return;

    // Issue independent loads early (overlap with compute below).
    const float hk = h[node * 32 + k];
    const float xv = (k < 3) ? x[node * 3 + k] : 0.0f;
    const float ba0 = ba[0];

    // ---- edge layer 1: acc = sum_f h[f]*(We1[f][k] + We1[f+32][k])
    //                        + SQRT_EPS*We1[64][k] + be1[k]
    float a0 = fmaf(SQRT_EPS, We1[64 * 32 + k], be1[k]);
    float a1 = 0.0f, a2 = 0.0f, a3 = 0.0f;
#pragma unroll
    for (int f = 0; f < 32; f += 4) {
        a0 = fmaf(__shfl(hk, f + 0, 32), We1[(f + 0) * 32 + k] + We1[(f + 32) * 32 + k], a0);
        a1 = fmaf(__shfl(hk, f + 1, 32), We1[(f + 1) * 32 + k] + We1[(f + 33) * 32 + k], a1);
        a2 = fmaf(__shfl(hk, f + 2, 32), We1[(f + 2) * 32 + k] + We1[(f + 34) * 32 + k], a2);
        a3 = fmaf(__shfl(hk, f + 3, 32), We1[(f + 3) * 32 + k] + We1[(f + 35) * 32 + k], a3);
    }
    const float t1 = silu_f((a0 + a1) + (a2 + a3));

    // ---- edge layer 2
    a0 = be2[k]; a1 = 0.0f; a2 = 0.0f; a3 = 0.0f;
#pragma unroll
    for (int f = 0; f < 32; f += 4) {
        a0 = fmaf(__shfl(t1, f + 0, 32), We2[(f + 0) * 32 + k], a0);
        a1 = fmaf(__shfl(t1, f + 1, 32), We2[(f + 1) * 32 + k], a1);
        a2 = fmaf(__shfl(t1, f + 2, 32), We2[(f + 2) * 32 + k], a2);
        a3 = fmaf(__shfl(t1, f + 3, 32), We2[(f + 3) * 32 + k], a3);
    }
    const float t2 = silu_f((a0 + a1) + (a2 + a3));

    // ---- attention gate: sigmoid(sum_k t2[k]*Wa[k][0] + ba)
    float av = t2 * Wa[k];
#pragma unroll
    for (int m = 16; m >= 1; m >>= 1) av += __shfl_xor(av, m, 32);
    const float att = 1.0f / (1.0f + expf(-(av + ba0)));
    const float he = att * t2;

    // ---- node MLP layer 1: n_in = [h(32), he(32)]; two independent 4-way chains
    a0 = bn1[k]; a1 = 0.0f; a2 = 0.0f; a3 = 0.0f;
    float b0 = 0.0f, b1 = 0.0f, b2 = 0.0f, b3 = 0.0f;
#pragma unroll
    for (int f = 0; f < 32; f += 4) {
        a0 = fmaf(__shfl(hk, f + 0, 32), Wn1[(f + 0) * 32 + k], a0);
        a1 = fmaf(__shfl(hk, f + 1, 32), Wn1[(f + 1) * 32 + k], a1);
        a2 = fmaf(__shfl(hk, f + 2, 32), Wn1[(f + 2) * 32 + k], a2);
        a3 = fmaf(__shfl(hk, f + 3, 32), Wn1[(f + 3) * 32 + k], a3);
        b0 = fmaf(__shfl(he, f + 0, 32), Wn1[(f + 32) * 32 + k], b0);
        b1 = fmaf(__shfl(he, f + 1, 32), Wn1[(f + 33) * 32 + k], b1);
        b2 = fmaf(__shfl(he, f + 2, 32), Wn1[(f + 34) * 32 + k], b2);
        b3 = fmaf(__shfl(he, f + 3, 32), Wn1[(f + 35) * 32 + k], b3);
    }
    const float u = silu_f(((a0 + a1) + (a2 + a3)) + ((b0 + b1) + (b2 + b3)));

    // ---- node MLP layer 2 (no activation)
    a0 = bn2[k]; a1 = 0.0f; a2 = 0.0f; a3 = 0.0f;
#pragma unroll
    for (int f = 0; f < 32; f += 4) {
        a0 = fmaf(__shfl(u, f + 0, 32), Wn2[(f + 0) * 32 + k], a0);
        a1 = fmaf(__shfl(u, f + 1, 32), Wn2[(f + 1) * 32 + k], a1);
        a2 = fmaf(__shfl(u, f + 2, 32), Wn2[(f + 2) * 32 + k], a2);
        a3 = fmaf(__shfl(u, f + 3, 32), Wn2[(f + 3) * 32 + k], a3);
    }
    out[node * 32 + k] = (a0 + a1) + (a2 + a3);

    // ---- x passthrough (second tuple element), fp32
    if (k < 3) out[n_nodes * 32 + node * 3 + k] = xv;
}

extern "C" void kernel_launch(void* const* d_in, const int* in_sizes, int n_in,
                              void* d_out, int out_size, void* d_ws, size_t ws_size,
                              hipStream_t stream) {
    const float* h   = (const float*)d_in[0];
    const float* x   = (const float*)d_in[1];
    const float* We1 = (const float*)d_in[2];
    const float* be1 = (const float*)d_in[3];
    const float* We2 = (const float*)d_in[4];
    const float* be2 = (const float*)d_in[5];
    const float* Wa  = (const float*)d_in[6];
    const float* ba  = (const float*)d_in[7];
    const float* Wn1 = (const float*)d_in[8];
    const float* bn1 = (const float*)d_in[9];
    const float* Wn2 = (const float*)d_in[10];
    const float* bn2 = (const float*)d_in[11];

    const int n_nodes = in_sizes[0] / 32;  // B*N = 2048
    const int threads = n_nodes * 32;
    const int block   = 256;
    const int grid    = (threads + block - 1) / block;

    egnn_diag_kernel<<<grid, block, 0, stream>>>(
        h, x, We1, be1, We2, be2, Wa, ba, Wn1, bn1, Wn2, bn2,
        (float*)d_out, n_nodes);
}